// Round 1
// baseline (6992.648 us; speedup 1.0000x reference)
//
#include <hip/hip_runtime.h>

#define NN 100000
#define EE 600000
#define DD 128
#define LL 5

typedef float f32x4 __attribute__((ext_vector_type(4)));
typedef __bf16 bf16x8 __attribute__((ext_vector_type(8)));

// ---------------- seed: h = sum of 6 atom-feature embeddings ----------------
__global__ __launch_bounds__(256) void seed_kernel(
    const int* __restrict__ an, const int* __restrict__ fc,
    const int* __restrict__ ct, const int* __restrict__ hy,
    const int* __restrict__ nh, const int* __restrict__ ar,
    const float* __restrict__ ean, const float* __restrict__ efc,
    const float* __restrict__ ect, const float* __restrict__ ehy,
    const float* __restrict__ enh, const float* __restrict__ ear,
    float* __restrict__ h)
{
    int idx = blockIdx.x * 256 + threadIdx.x;   // covers NN*32 exactly
    int n = idx >> 5, q = idx & 31;
    f32x4 v = ((const f32x4*)(ean + an[n] * DD))[q];
    v += ((const f32x4*)(efc + fc[n] * DD))[q];
    v += ((const f32x4*)(ect + ct[n] * DD))[q];
    v += ((const f32x4*)(ehy + hy[n] * DD))[q];
    v += ((const f32x4*)(enh + nh[n] * DD))[q];
    v += ((const f32x4*)(ear + ar[n] * DD))[q];
    ((f32x4*)h)[idx] = v;
}

// ---------------- weight convert+transpose to bf16 [n][k] ----------------
__global__ __launch_bounds__(256) void convw1_kernel(const float* __restrict__ w1,
                                                     __bf16* __restrict__ w1t)
{
    int idx = blockIdx.x * 256 + threadIdx.x;   // 5*256*128
    int l = idx >> 15, rem = idx & 32767;
    int n = rem >> 7, k = rem & 127;
    w1t[idx] = (__bf16)w1[l * 32768 + k * 256 + n];
}
__global__ __launch_bounds__(256) void convw2_kernel(const float* __restrict__ w2,
                                                     __bf16* __restrict__ w2t)
{
    int idx = blockIdx.x * 256 + threadIdx.x;   // 5*128*256
    int l = idx >> 15, rem = idx & 32767;
    int n = rem >> 8, k = rem & 255;
    w2t[idx] = (__bf16)w2[l * 32768 + k * 128 + n];
}

// ---------------- agg = h + self_vec ----------------
__global__ __launch_bounds__(256) void init_agg_kernel(
    const float* __restrict__ h, float* __restrict__ agg,
    const float* __restrict__ ec, const float* __restrict__ ea,
    const float* __restrict__ eb, const float* __restrict__ ed,
    const float* __restrict__ es)
{
    int idx = blockIdx.x * 256 + threadIdx.x;   // NN*32
    int q = idx & 31;
    f32x4 sv = ((const f32x4*)ec)[q] + ((const f32x4*)ea)[q] + ((const f32x4*)eb)[q]
             + ((const f32x4*)ed)[q] + ((const f32x4*)es)[q];
    ((f32x4*)agg)[idx] = ((const f32x4*)h)[idx] + sv;
}

// ---------------- edge scatter: agg[dst] += h[src] + eemb ----------------
__global__ __launch_bounds__(256) void scatter_kernel(
    const float* __restrict__ h, float* __restrict__ agg,
    const int* __restrict__ ei,
    const int* __restrict__ f0, const int* __restrict__ f1,
    const int* __restrict__ f2, const int* __restrict__ f3,
    const int* __restrict__ f4,
    const float* __restrict__ t0, const float* __restrict__ t1,
    const float* __restrict__ t2, const float* __restrict__ t3,
    const float* __restrict__ t4)
{
    int idx = blockIdx.x * 256 + threadIdx.x;   // EE*32
    int e = idx >> 5, q = idx & 31;
    int src = ei[e], dst = ei[EE + e];
    f32x4 v = ((const f32x4*)(h + src * DD))[q];
    v += ((const f32x4*)(t0 + f0[e] * DD))[q];
    v += ((const f32x4*)(t1 + f1[e] * DD))[q];
    v += ((const f32x4*)(t2 + f2[e] * DD))[q];
    v += ((const f32x4*)(t3 + f3[e] * DD))[q];
    v += ((const f32x4*)(t4 + f4[e] * DD))[q];
    float* o = agg + dst * DD + q * 4;
    atomicAdd(o + 0, v.x);
    atomicAdd(o + 1, v.y);
    atomicAdd(o + 2, v.z);
    atomicAdd(o + 3, v.w);
}

// ---------------- GEMM1: hid = relu(agg @ W1 + b1), bf16 out ----------------
// A fp32 [M][128], w1t bf16 [256][128], block = 64 rows x 128 cols (grid.y=2)
__global__ __launch_bounds__(256) void gemm1_kernel(
    const float* __restrict__ A, const __bf16* __restrict__ w1t,
    const float* __restrict__ b1, __bf16* __restrict__ hid, int M)
{
    __shared__ __bf16 lds[128 * 136];           // +8 pad breaks bank conflicts
    int nb = blockIdx.y;
    int tid = threadIdx.x;
    for (int i = tid; i < 2048; i += 256) {     // 128 rows x 16 chunks of 8 bf16
        int r = i >> 4, c = i & 15;
        *(bf16x8*)(&lds[r * 136 + c * 8]) =
            *(const bf16x8*)(w1t + (nb * 128 + r) * 128 + c * 8);
    }
    __syncthreads();

    int wave = tid >> 6, lane = tid & 63;
    int ln = lane & 15, quad = lane >> 4;
    int row0 = blockIdx.x * 64 + wave * 16;
    int m = row0 + ln;
    bool valid = m < M;

    f32x4 acc[8] = {};
    #pragma unroll
    for (int s = 0; s < 4; ++s) {               // K=128
        int kb = s * 32 + quad * 8;
        bf16x8 af = {};
        if (valid) {
            const float* ap = A + m * 128 + kb;
            f32x4 a0 = *(const f32x4*)ap;
            f32x4 a1 = *(const f32x4*)(ap + 4);
            #pragma unroll
            for (int j = 0; j < 4; ++j) { af[j] = (__bf16)a0[j]; af[j + 4] = (__bf16)a1[j]; }
        }
        #pragma unroll
        for (int t = 0; t < 8; ++t) {
            bf16x8 bf = *(const bf16x8*)(&lds[(t * 16 + ln) * 136 + kb]);
            acc[t] = __builtin_amdgcn_mfma_f32_16x16x32_bf16(af, bf, acc[t], 0, 0, 0);
        }
    }
    #pragma unroll
    for (int t = 0; t < 8; ++t) {
        int n = nb * 128 + t * 16 + ln;
        float bias = b1[n];
        #pragma unroll
        for (int r = 0; r < 4; ++r) {
            int row = row0 + quad * 4 + r;
            if (row < M) {
                float v = acc[t][r] + bias;
                v = v > 0.f ? v : 0.f;
                hid[row * 256 + n] = (__bf16)v;
            }
        }
    }
}

// ---------------- GEMM2: hpre = hid @ W2 + b2 (fp32) + BN col stats ----------------
// A bf16 [M][256], w2t bf16 [128][256], block = 64 rows x 64 cols (grid.y=2)
__global__ __launch_bounds__(256) void gemm2_kernel(
    const __bf16* __restrict__ A, const __bf16* __restrict__ w2t,
    const float* __restrict__ b2, float* __restrict__ hpre,
    float* __restrict__ colsum, float* __restrict__ colsumsq, int M)
{
    __shared__ __bf16 lds[64 * 264];            // 256 + 8 pad
    int nb = blockIdx.y;
    int tid = threadIdx.x;
    for (int i = tid; i < 2048; i += 256) {     // 64 rows x 32 chunks of 8 bf16
        int r = i >> 5, c = i & 31;
        *(bf16x8*)(&lds[r * 264 + c * 8]) =
            *(const bf16x8*)(w2t + (nb * 64 + r) * 256 + c * 8);
    }
    __syncthreads();

    int wave = tid >> 6, lane = tid & 63;
    int ln = lane & 15, quad = lane >> 4;
    int row0 = blockIdx.x * 64 + wave * 16;
    int m = row0 + ln;
    bool valid = m < M;

    f32x4 acc[4] = {};
    #pragma unroll
    for (int s = 0; s < 8; ++s) {               // K=256
        int kb = s * 32 + quad * 8;
        bf16x8 af = {};
        if (valid) af = *(const bf16x8*)(A + m * 256 + kb);
        #pragma unroll
        for (int t = 0; t < 4; ++t) {
            bf16x8 bf = *(const bf16x8*)(&lds[(t * 16 + ln) * 264 + kb]);
            acc[t] = __builtin_amdgcn_mfma_f32_16x16x32_bf16(af, bf, acc[t], 0, 0, 0);
        }
    }
    #pragma unroll
    for (int t = 0; t < 4; ++t) {
        int n = nb * 64 + t * 16 + ln;
        float bias = b2[n];
        float s = 0.f, q = 0.f;
        #pragma unroll
        for (int r = 0; r < 4; ++r) {
            int row = row0 + quad * 4 + r;
            float v = 0.f;
            if (row < M) {
                v = acc[t][r] + bias;
                hpre[row * 128 + n] = v;
            }
            s += v; q += v * v;
        }
        s += __shfl_xor(s, 16, 64); s += __shfl_xor(s, 32, 64);
        q += __shfl_xor(q, 16, 64); q += __shfl_xor(q, 32, 64);
        if (lane < 16) {
            atomicAdd(&colsum[n], s);
            atomicAdd(&colsumsq[n], q);
        }
    }
}

// ---------------- BN apply (+ optional relu) ----------------
__global__ __launch_bounds__(256) void bn_kernel(
    const float* __restrict__ hpre, float* __restrict__ out,
    const float* __restrict__ colsum, const float* __restrict__ colsumsq,
    const float* __restrict__ gamma, const float* __restrict__ beta,
    int relu)
{
    int idx = blockIdx.x * 256 + threadIdx.x;   // NN*32
    int q = idx & 31;
    f32x4 x = ((const f32x4*)hpre)[idx];
    const float invN = 1.0f / NN;
    f32x4 y;
    #pragma unroll
    for (int j = 0; j < 4; ++j) {
        int c = q * 4 + j;
        float mean = colsum[c] * invN;
        float var = colsumsq[c] * invN - mean * mean;
        float inv = rsqrtf(var + 1e-5f);
        float v = gamma[c] * (x[j] - mean) * inv + beta[c];
        y[j] = (relu && v < 0.f) ? 0.f : v;
    }
    ((f32x4*)out)[idx] = y;
}

extern "C" void kernel_launch(void* const* d_in, const int* in_sizes, int n_in,
                              void* d_out, int out_size, void* d_ws, size_t ws_size,
                              hipStream_t stream)
{
    const int* an  = (const int*)d_in[0];
    const int* fc  = (const int*)d_in[1];
    const int* ct  = (const int*)d_in[2];
    const int* hy  = (const int*)d_in[3];
    const int* nh  = (const int*)d_in[4];
    const int* ar  = (const int*)d_in[5];
    const int* ei  = (const int*)d_in[6];
    const int* econ = (const int*)d_in[7];
    const int* earo = (const int*)d_in[8];
    const int* ebt  = (const int*)d_in[9];
    const int* ebd  = (const int*)d_in[10];
    const int* ebs  = (const int*)d_in[11];
    const float* ean = (const float*)d_in[12];
    const float* efc = (const float*)d_in[13];
    const float* ect = (const float*)d_in[14];
    const float* ehy = (const float*)d_in[15];
    const float* enh = (const float*)d_in[16];
    const float* ear = (const float*)d_in[17];
    const float* e_conj   = (const float*)d_in[18];   // [5,3,128]
    const float* e_arom   = (const float*)d_in[19];   // [5,3,128]
    const float* e_btype  = (const float*)d_in[20];   // [5,23,128]
    const float* e_bdir   = (const float*)d_in[21];   // [5,8,128]
    const float* e_bstereo= (const float*)d_in[22];   // [5,7,128]
    const float* mlp_w1 = (const float*)d_in[23];     // [5,128,256]
    const float* mlp_b1 = (const float*)d_in[24];     // [5,256]
    const float* mlp_w2 = (const float*)d_in[25];     // [5,256,128]
    const float* mlp_b2 = (const float*)d_in[26];     // [5,128]
    const float* bn_gamma = (const float*)d_in[27];   // [5,128]
    const float* bn_beta  = (const float*)d_in[28];   // [5,128]

    // workspace carve (all 256B-aligned)
    float*  h    = (float*)d_ws;                      // N*128 f32 = 51.2 MB
    float*  agg  = h + NN * DD;                       // N*128 f32 (doubles as hpre)
    __bf16* hid  = (__bf16*)(agg + NN * DD);          // N*256 bf16 = 51.2 MB
    __bf16* w1t  = (__bf16*)(hid + (size_t)NN * 256); // 5*256*128 bf16
    __bf16* w2t  = w1t + LL * 256 * 128;              // 5*128*256 bf16
    float*  colsum   = (float*)(w2t + LL * 128 * 256);
    float*  colsumsq = colsum + 128;

    convw1_kernel<<<640, 256, 0, stream>>>(mlp_w1, w1t);
    convw2_kernel<<<640, 256, 0, stream>>>(mlp_w2, w2t);
    seed_kernel<<<12500, 256, 0, stream>>>(an, fc, ct, hy, nh, ar,
                                           ean, efc, ect, ehy, enh, ear, h);

    for (int l = 0; l < LL; ++l) {
        const float* tc = e_conj   + l * 3 * DD;
        const float* ta = e_arom   + l * 3 * DD;
        const float* tb = e_btype  + l * 23 * DD;
        const float* td = e_bdir   + l * 8 * DD;
        const float* ts = e_bstereo+ l * 7 * DD;

        init_agg_kernel<<<12500, 256, 0, stream>>>(h, agg, tc, ta, tb, td, ts);
        scatter_kernel<<<75000, 256, 0, stream>>>(h, agg, ei,
                                                  econ, earo, ebt, ebd, ebs,
                                                  tc, ta, tb, td, ts);
        gemm1_kernel<<<dim3(1563, 2), 256, 0, stream>>>(
            agg, w1t + l * 32768, mlp_b1 + l * 256, hid, NN);
        hipMemsetAsync(colsum, 0, 256 * sizeof(float), stream);
        gemm2_kernel<<<dim3(1563, 2), 256, 0, stream>>>(
            hid, w2t + l * 32768, mlp_b2 + l * 128, agg, colsum, colsumsq, NN);
        bn_kernel<<<12500, 256, 0, stream>>>(
            agg, (l == LL - 1) ? (float*)d_out : h, colsum, colsumsq,
            bn_gamma + l * 128, bn_beta + l * 128, (l < LL - 1) ? 1 : 0);
    }
}

// Round 2
// 2422.329 us; speedup vs baseline: 2.8867x; 2.8867x over previous
//
#include <hip/hip_runtime.h>

#define NN 100000
#define EE 600000
#define DD 128
#define LL 5
#define CTROWS 5152   // 2*2*23*8*7 combined edge-feature rows

typedef float f32x4 __attribute__((ext_vector_type(4)));
typedef _Float16 f16x8 __attribute__((ext_vector_type(8)));

// ---------------- seed: h = sum of 6 atom-feature embeddings ----------------
__global__ __launch_bounds__(256) void seed_kernel(
    const int* __restrict__ an, const int* __restrict__ fc,
    const int* __restrict__ ct, const int* __restrict__ hy,
    const int* __restrict__ nh, const int* __restrict__ ar,
    const float* __restrict__ ean, const float* __restrict__ efc,
    const float* __restrict__ ect, const float* __restrict__ ehy,
    const float* __restrict__ enh, const float* __restrict__ ear,
    float* __restrict__ h)
{
    int idx = blockIdx.x * 256 + threadIdx.x;   // covers NN*32 exactly
    int n = idx >> 5, q = idx & 31;
    f32x4 v = ((const f32x4*)(ean + an[n] * DD))[q];
    v += ((const f32x4*)(efc + fc[n] * DD))[q];
    v += ((const f32x4*)(ect + ct[n] * DD))[q];
    v += ((const f32x4*)(ehy + hy[n] * DD))[q];
    v += ((const f32x4*)(enh + nh[n] * DD))[q];
    v += ((const f32x4*)(ear + ar[n] * DD))[q];
    ((f32x4*)h)[idx] = v;
}

// ---------------- weight convert+transpose to fp16 [n][k] ----------------
__global__ __launch_bounds__(256) void convw1_kernel(const float* __restrict__ w1,
                                                     _Float16* __restrict__ w1t)
{
    int idx = blockIdx.x * 256 + threadIdx.x;   // 5*256*128
    int l = idx >> 15, rem = idx & 32767;
    int n = rem >> 7, k = rem & 127;
    w1t[idx] = (_Float16)w1[l * 32768 + k * 256 + n];
}
__global__ __launch_bounds__(256) void convw2_kernel(const float* __restrict__ w2,
                                                     _Float16* __restrict__ w2t)
{
    int idx = blockIdx.x * 256 + threadIdx.x;   // 5*128*256
    int l = idx >> 15, rem = idx & 32767;
    int n = rem >> 8, k = rem & 255;
    w2t[idx] = (_Float16)w2[l * 32768 + k * 128 + n];
}

// ---------------- CSR build: count, scan, fill ----------------
__global__ __launch_bounds__(256) void count_kernel(const int* __restrict__ ei,
                                                    int* __restrict__ cursor)
{
    int e = blockIdx.x * 256 + threadIdx.x;
    if (e < EE) atomicAdd(&cursor[ei[EE + e]], 1);
}

// single-block scan: reads counts from cursor, writes exclusive prefix into
// rowstart[0..NN] AND back into cursor (fill cursor)
__global__ __launch_bounds__(1024) void scan_kernel(int* __restrict__ cursor,
                                                    int* __restrict__ rowstart)
{
    __shared__ int wsum[16];
    int tid = threadIdx.x;
    int lane = tid & 63, wv = tid >> 6;
    int carry = 0;
    for (int base = 0; base < NN; base += 8192) {
        int i0 = base + tid * 8;
        int v[8]; int s = 0;
        #pragma unroll
        for (int j = 0; j < 8; ++j) {
            int idx = i0 + j;
            int x = (idx < NN) ? cursor[idx] : 0;
            v[j] = s; s += x;
        }
        int incl = s;
        #pragma unroll
        for (int off = 1; off < 64; off <<= 1) {
            int t = __shfl_up(incl, off, 64);
            if (lane >= off) incl += t;
        }
        if (lane == 63) wsum[wv] = incl;
        __syncthreads();
        int woff = 0, total = 0;
        #pragma unroll
        for (int w = 0; w < 16; ++w) {
            int ws = wsum[w];
            woff += (w < wv) ? ws : 0;
            total += ws;
        }
        int texcl = carry + woff + incl - s;
        #pragma unroll
        for (int j = 0; j < 8; ++j) {
            int idx = i0 + j;
            if (idx < NN) { int e = texcl + v[j]; rowstart[idx] = e; cursor[idx] = e; }
        }
        carry += total;
        __syncthreads();
    }
    if (tid == 0) rowstart[NN] = carry;
}

// fill: rec[p] = src | (combined_feat << 17)
__global__ __launch_bounds__(256) void fill_kernel(
    const int* __restrict__ ei, int* __restrict__ cursor, int* __restrict__ rec,
    const int* __restrict__ f0, const int* __restrict__ f1,
    const int* __restrict__ f2, const int* __restrict__ f3,
    const int* __restrict__ f4)
{
    int e = blockIdx.x * 256 + threadIdx.x;
    if (e >= EE) return;
    int dst = ei[EE + e];
    int p = atomicAdd(&cursor[dst], 1);
    int f = f0[e] + 2 * (f1[e] + 2 * (f2[e] + 23 * (f3[e] + 8 * f4[e])));
    rec[p] = ei[e] | (f << 17);
}

// ---------------- combined edge-embedding table for one layer ----------------
__global__ __launch_bounds__(256) void ctab_kernel(
    const float* __restrict__ ec, const float* __restrict__ ea,
    const float* __restrict__ eb, const float* __restrict__ ed,
    const float* __restrict__ es, float* __restrict__ ctab)
{
    int idx = blockIdx.x * 256 + threadIdx.x;   // CTROWS*32 exactly
    int row = idx >> 5, q = idx & 31;
    int conj = row & 1, arom = (row >> 1) & 1;
    int r2 = row >> 2;
    int bt = r2 % 23, r3 = r2 / 23;
    int bd = r3 & 7, bs = r3 >> 3;
    f32x4 v = ((const f32x4*)(ec + conj * DD))[q]
            + ((const f32x4*)(ea + arom * DD))[q]
            + ((const f32x4*)(eb + bt * DD))[q]
            + ((const f32x4*)(ed + bd * DD))[q]
            + ((const f32x4*)(es + bs * DD))[q];
    ((f32x4*)ctab)[idx] = v;
}

// ---------------- gather-aggregate: agg = h + self_vec + sum over CSR row ----
__global__ __launch_bounds__(256) void gather_kernel(
    const float* __restrict__ h, float* __restrict__ agg,
    const int* __restrict__ rowstart, const int* __restrict__ rec,
    const float* __restrict__ ctab)
{
    int idx = blockIdx.x * 256 + threadIdx.x;   // NN*32
    int n = idx >> 5, q = idx & 31;
    int p0 = rowstart[n], p1 = rowstart[n + 1];
    // self_vec == ctab row 0 (all self-loop feature indices are 0)
    f32x4 v = ((const f32x4*)(h + n * DD))[q] + ((const f32x4*)ctab)[q];
    for (int p = p0; p < p1; ++p) {
        int r = rec[p];
        int s = r & 0x1FFFF, f = r >> 17;
        v += ((const f32x4*)(h + s * DD))[q];
        v += ((const f32x4*)(ctab + f * DD))[q];
    }
    ((f32x4*)agg)[idx] = v;
}

// ---------------- GEMM1: hid = relu(agg @ W1 + b1), fp16 out ----------------
// A fp32 [M][128], w1t fp16 [256][128], block = 64 rows x 128 cols (grid.y=2)
__global__ __launch_bounds__(256) void gemm1_kernel(
    const float* __restrict__ A, const _Float16* __restrict__ w1t,
    const float* __restrict__ b1, _Float16* __restrict__ hid, int M)
{
    __shared__ _Float16 lds[128 * 136];         // +8 pad
    int nb = blockIdx.y;
    int tid = threadIdx.x;
    for (int i = tid; i < 2048; i += 256) {     // 128 rows x 16 chunks of 8 fp16
        int r = i >> 4, c = i & 15;
        *(f16x8*)(&lds[r * 136 + c * 8]) =
            *(const f16x8*)(w1t + (nb * 128 + r) * 128 + c * 8);
    }
    __syncthreads();

    int wave = tid >> 6, lane = tid & 63;
    int ln = lane & 15, quad = lane >> 4;
    int row0 = blockIdx.x * 64 + wave * 16;
    int m = row0 + ln;
    bool valid = m < M;

    f32x4 acc[8] = {};
    #pragma unroll
    for (int s = 0; s < 4; ++s) {               // K=128
        int kb = s * 32 + quad * 8;
        f16x8 af = {};
        if (valid) {
            const float* ap = A + m * 128 + kb;
            f32x4 a0 = *(const f32x4*)ap;
            f32x4 a1 = *(const f32x4*)(ap + 4);
            #pragma unroll
            for (int j = 0; j < 4; ++j) { af[j] = (_Float16)a0[j]; af[j + 4] = (_Float16)a1[j]; }
        }
        #pragma unroll
        for (int t = 0; t < 8; ++t) {
            f16x8 bf = *(const f16x8*)(&lds[(t * 16 + ln) * 136 + kb]);
            acc[t] = __builtin_amdgcn_mfma_f32_16x16x32_f16(af, bf, acc[t], 0, 0, 0);
        }
    }
    #pragma unroll
    for (int t = 0; t < 8; ++t) {
        int n = nb * 128 + t * 16 + ln;
        float bias = b1[n];
        #pragma unroll
        for (int r = 0; r < 4; ++r) {
            int row = row0 + quad * 4 + r;
            if (row < M) {
                float v = acc[t][r] + bias;
                v = v > 0.f ? v : 0.f;
                hid[row * 256 + n] = (_Float16)v;
            }
        }
    }
}

// ---------------- GEMM2: hpre = hid @ W2 + b2 (fp32) + BN col stats ----------
// A fp16 [M][256], w2t fp16 [128][256], block = 64 rows x 64 cols (grid.y=2)
__global__ __launch_bounds__(256) void gemm2_kernel(
    const _Float16* __restrict__ A, const _Float16* __restrict__ w2t,
    const float* __restrict__ b2, float* __restrict__ hpre,
    float* __restrict__ colsum, float* __restrict__ colsumsq, int M)
{
    __shared__ _Float16 lds[64 * 264];          // 256 + 8 pad
    int nb = blockIdx.y;
    int tid = threadIdx.x;
    for (int i = tid; i < 2048; i += 256) {     // 64 rows x 32 chunks of 8 fp16
        int r = i >> 5, c = i & 31;
        *(f16x8*)(&lds[r * 264 + c * 8]) =
            *(const f16x8*)(w2t + (nb * 64 + r) * 256 + c * 8);
    }
    __syncthreads();

    int wave = tid >> 6, lane = tid & 63;
    int ln = lane & 15, quad = lane >> 4;
    int row0 = blockIdx.x * 64 + wave * 16;
    int m = row0 + ln;
    bool valid = m < M;

    f32x4 acc[4] = {};
    #pragma unroll
    for (int s = 0; s < 8; ++s) {               // K=256
        int kb = s * 32 + quad * 8;
        f16x8 af = {};
        if (valid) af = *(const f16x8*)(A + m * 256 + kb);
        #pragma unroll
        for (int t = 0; t < 4; ++t) {
            f16x8 bf = *(const f16x8*)(&lds[(t * 16 + ln) * 264 + kb]);
            acc[t] = __builtin_amdgcn_mfma_f32_16x16x32_f16(af, bf, acc[t], 0, 0, 0);
        }
    }
    #pragma unroll
    for (int t = 0; t < 4; ++t) {
        int n = nb * 64 + t * 16 + ln;
        float bias = b2[n];
        float s = 0.f, q = 0.f;
        #pragma unroll
        for (int r = 0; r < 4; ++r) {
            int row = row0 + quad * 4 + r;
            float v = 0.f;
            if (row < M) {
                v = acc[t][r] + bias;
                hpre[row * 128 + n] = v;
            }
            s += v; q += v * v;
        }
        s += __shfl_xor(s, 16, 64); s += __shfl_xor(s, 32, 64);
        q += __shfl_xor(q, 16, 64); q += __shfl_xor(q, 32, 64);
        if (lane < 16) {
            atomicAdd(&colsum[n], s);
            atomicAdd(&colsumsq[n], q);
        }
    }
}

// ---------------- BN apply (+ optional relu) ----------------
__global__ __launch_bounds__(256) void bn_kernel(
    const float* __restrict__ hpre, float* __restrict__ out,
    const float* __restrict__ colsum, const float* __restrict__ colsumsq,
    const float* __restrict__ gamma, const float* __restrict__ beta,
    int relu)
{
    int idx = blockIdx.x * 256 + threadIdx.x;   // NN*32
    int q = idx & 31;
    f32x4 x = ((const f32x4*)hpre)[idx];
    const float invN = 1.0f / NN;
    f32x4 y;
    #pragma unroll
    for (int j = 0; j < 4; ++j) {
        int c = q * 4 + j;
        float mean = colsum[c] * invN;
        float var = colsumsq[c] * invN - mean * mean;
        float inv = rsqrtf(var + 1e-5f);
        float v = gamma[c] * (x[j] - mean) * inv + beta[c];
        y[j] = (relu && v < 0.f) ? 0.f : v;
    }
    ((f32x4*)out)[idx] = y;
}

extern "C" void kernel_launch(void* const* d_in, const int* in_sizes, int n_in,
                              void* d_out, int out_size, void* d_ws, size_t ws_size,
                              hipStream_t stream)
{
    const int* an  = (const int*)d_in[0];
    const int* fc  = (const int*)d_in[1];
    const int* ct  = (const int*)d_in[2];
    const int* hy  = (const int*)d_in[3];
    const int* nh  = (const int*)d_in[4];
    const int* ar  = (const int*)d_in[5];
    const int* ei  = (const int*)d_in[6];
    const int* econ = (const int*)d_in[7];
    const int* earo = (const int*)d_in[8];
    const int* ebt  = (const int*)d_in[9];
    const int* ebd  = (const int*)d_in[10];
    const int* ebs  = (const int*)d_in[11];
    const float* ean = (const float*)d_in[12];
    const float* efc = (const float*)d_in[13];
    const float* ect = (const float*)d_in[14];
    const float* ehy = (const float*)d_in[15];
    const float* enh = (const float*)d_in[16];
    const float* ear = (const float*)d_in[17];
    const float* e_conj   = (const float*)d_in[18];   // [5,3,128]
    const float* e_arom   = (const float*)d_in[19];   // [5,3,128]
    const float* e_btype  = (const float*)d_in[20];   // [5,23,128]
    const float* e_bdir   = (const float*)d_in[21];   // [5,8,128]
    const float* e_bstereo= (const float*)d_in[22];   // [5,7,128]
    const float* mlp_w1 = (const float*)d_in[23];     // [5,128,256]
    const float* mlp_b1 = (const float*)d_in[24];     // [5,256]
    const float* mlp_w2 = (const float*)d_in[25];     // [5,256,128]
    const float* mlp_b2 = (const float*)d_in[26];     // [5,128]
    const float* bn_gamma = (const float*)d_in[27];   // [5,128]
    const float* bn_beta  = (const float*)d_in[28];   // [5,128]

    // workspace carve (base is 256B-aligned; every segment keeps 16B alignment)
    float*    h    = (float*)d_ws;                      // N*128 f32
    float*    agg  = h + NN * DD;                       // N*128 f32 (doubles as hpre)
    _Float16* hid  = (_Float16*)(agg + NN * DD);        // N*256 fp16
    _Float16* w1t  = hid + (size_t)NN * 256;            // 5*256*128 fp16
    _Float16* w2t  = w1t + LL * 256 * 128;              // 5*128*256 fp16
    float*    colsum   = (float*)(w2t + LL * 128 * 256);
    float*    colsumsq = colsum + 128;
    float*    ctab = colsumsq + 128;                    // CTROWS*128 f32 (per layer)
    int* rowstart = (int*)(ctab + CTROWS * DD);         // NN+1
    int* cursor   = rowstart + NN + 8;                  // NN (padded start)
    int* rec      = cursor + NN;                        // EE
    // total ≈ 160.1 MB

    convw1_kernel<<<640, 256, 0, stream>>>(mlp_w1, w1t);
    convw2_kernel<<<640, 256, 0, stream>>>(mlp_w2, w2t);
    seed_kernel<<<12500, 256, 0, stream>>>(an, fc, ct, hy, nh, ar,
                                           ean, efc, ect, ehy, enh, ear, h);

    // CSR build (graph is layer-invariant; ws is re-poisoned every call so
    // this must run every call)
    hipMemsetAsync(cursor, 0, NN * sizeof(int), stream);
    count_kernel<<<2344, 256, 0, stream>>>(ei, cursor);
    scan_kernel<<<1, 1024, 0, stream>>>(cursor, rowstart);
    fill_kernel<<<2344, 256, 0, stream>>>(ei, cursor, rec,
                                          econ, earo, ebt, ebd, ebs);

    for (int l = 0; l < LL; ++l) {
        ctab_kernel<<<644, 256, 0, stream>>>(
            e_conj + l * 3 * DD, e_arom + l * 3 * DD, e_btype + l * 23 * DD,
            e_bdir + l * 8 * DD, e_bstereo + l * 7 * DD, ctab);
        gather_kernel<<<12500, 256, 0, stream>>>(h, agg, rowstart, rec, ctab);
        gemm1_kernel<<<dim3(1563, 2), 256, 0, stream>>>(
            agg, w1t + l * 32768, mlp_b1 + l * 256, hid, NN);
        hipMemsetAsync(colsum, 0, 256 * sizeof(float), stream);
        gemm2_kernel<<<dim3(1563, 2), 256, 0, stream>>>(
            hid, w2t + l * 32768, mlp_b2 + l * 128, agg, colsum, colsumsq, NN);
        bn_kernel<<<12500, 256, 0, stream>>>(
            agg, (l == LL - 1) ? (float*)d_out : h, colsum, colsumsq,
            bn_gamma + l * 128, bn_beta + l * 128, (l < LL - 1) ? 1 : 0);
    }
}

// Round 3
// 1099.347 us; speedup vs baseline: 6.3607x; 2.2034x over previous
//
#include <hip/hip_runtime.h>

#define NN 100000
#define EE 600000
#define DD 128
#define LL 5
#define CTROWS 5152   // 2*2*23*8*7 combined edge-feature rows
#define MBLK 1563     // ceil(NN/64)

typedef float f32x4 __attribute__((ext_vector_type(4)));
typedef _Float16 f16x8 __attribute__((ext_vector_type(8)));

// ---------------- seed: h = sum of 6 atom-feature embeddings ----------------
__global__ __launch_bounds__(256) void seed_kernel(
    const int* __restrict__ an, const int* __restrict__ fc,
    const int* __restrict__ ct, const int* __restrict__ hy,
    const int* __restrict__ nh, const int* __restrict__ ar,
    const float* __restrict__ ean, const float* __restrict__ efc,
    const float* __restrict__ ect, const float* __restrict__ ehy,
    const float* __restrict__ enh, const float* __restrict__ ear,
    float* __restrict__ h)
{
    int idx = blockIdx.x * 256 + threadIdx.x;   // covers NN*32 exactly
    int n = idx >> 5, q = idx & 31;
    f32x4 v = ((const f32x4*)(ean + an[n] * DD))[q];
    v += ((const f32x4*)(efc + fc[n] * DD))[q];
    v += ((const f32x4*)(ect + ct[n] * DD))[q];
    v += ((const f32x4*)(ehy + hy[n] * DD))[q];
    v += ((const f32x4*)(enh + nh[n] * DD))[q];
    v += ((const f32x4*)(ear + ar[n] * DD))[q];
    ((f32x4*)h)[idx] = v;
}

// ---------------- weight convert+transpose to fp16 [n][k] ----------------
__global__ __launch_bounds__(256) void convw1_kernel(const float* __restrict__ w1,
                                                     _Float16* __restrict__ w1t)
{
    int idx = blockIdx.x * 256 + threadIdx.x;   // 5*256*128
    int l = idx >> 15, rem = idx & 32767;
    int n = rem >> 7, k = rem & 127;
    w1t[idx] = (_Float16)w1[l * 32768 + k * 256 + n];
}
__global__ __launch_bounds__(256) void convw2_kernel(const float* __restrict__ w2,
                                                     _Float16* __restrict__ w2t)
{
    int idx = blockIdx.x * 256 + threadIdx.x;   // 5*128*256
    int l = idx >> 15, rem = idx & 32767;
    int n = rem >> 8, k = rem & 255;
    w2t[idx] = (_Float16)w2[l * 32768 + k * 128 + n];
}

// ---------------- identity scale/shift for layer-0 gather ----------------
__global__ void idss_kernel(float* __restrict__ idss)
{
    int t = threadIdx.x;
    idss[t] = (t < 128) ? 1.0f : 0.0f;
}

// ---------------- CSR build: count, scan, fill ----------------
__global__ __launch_bounds__(256) void count_kernel(const int* __restrict__ ei,
                                                    int* __restrict__ cursor)
{
    int e = blockIdx.x * 256 + threadIdx.x;
    if (e < EE) atomicAdd(&cursor[ei[EE + e]], 1);
}

__global__ __launch_bounds__(1024) void scan_kernel(int* __restrict__ cursor,
                                                    int* __restrict__ rowstart)
{
    __shared__ int wsum[16];
    int tid = threadIdx.x;
    int lane = tid & 63, wv = tid >> 6;
    int carry = 0;
    for (int base = 0; base < NN; base += 8192) {
        int i0 = base + tid * 8;
        int v[8]; int s = 0;
        #pragma unroll
        for (int j = 0; j < 8; ++j) {
            int idx = i0 + j;
            int x = (idx < NN) ? cursor[idx] : 0;
            v[j] = s; s += x;
        }
        int incl = s;
        #pragma unroll
        for (int off = 1; off < 64; off <<= 1) {
            int t = __shfl_up(incl, off, 64);
            if (lane >= off) incl += t;
        }
        if (lane == 63) wsum[wv] = incl;
        __syncthreads();
        int woff = 0, total = 0;
        #pragma unroll
        for (int w = 0; w < 16; ++w) {
            int ws = wsum[w];
            woff += (w < wv) ? ws : 0;
            total += ws;
        }
        int texcl = carry + woff + incl - s;
        #pragma unroll
        for (int j = 0; j < 8; ++j) {
            int idx = i0 + j;
            if (idx < NN) { int e = texcl + v[j]; rowstart[idx] = e; cursor[idx] = e; }
        }
        carry += total;
        __syncthreads();
    }
    if (tid == 0) rowstart[NN] = carry;
}

__global__ __launch_bounds__(256) void fill_kernel(
    const int* __restrict__ ei, int* __restrict__ cursor, int* __restrict__ rec,
    const int* __restrict__ f0, const int* __restrict__ f1,
    const int* __restrict__ f2, const int* __restrict__ f3,
    const int* __restrict__ f4)
{
    int e = blockIdx.x * 256 + threadIdx.x;
    if (e >= EE) return;
    int dst = ei[EE + e];
    int p = atomicAdd(&cursor[dst], 1);
    int f = f0[e] + 2 * (f1[e] + 2 * (f2[e] + 23 * (f3[e] + 8 * f4[e])));
    rec[p] = ei[e] | (f << 17);
}

// ---------------- combined edge-embedding table for one layer ----------------
__global__ __launch_bounds__(256) void ctab_kernel(
    const float* __restrict__ ec, const float* __restrict__ ea,
    const float* __restrict__ eb, const float* __restrict__ ed,
    const float* __restrict__ es, float* __restrict__ ctab)
{
    int idx = blockIdx.x * 256 + threadIdx.x;   // CTROWS*32 exactly
    int row = idx >> 5, q = idx & 31;
    int conj = row & 1, arom = (row >> 1) & 1;
    int r2 = row >> 2;
    int bt = r2 % 23, r3 = r2 / 23;
    int bd = r3 & 7, bs = r3 >> 3;
    f32x4 v = ((const f32x4*)(ec + conj * DD))[q]
            + ((const f32x4*)(ea + arom * DD))[q]
            + ((const f32x4*)(eb + bt * DD))[q]
            + ((const f32x4*)(ed + bd * DD))[q]
            + ((const f32x4*)(es + bs * DD))[q];
    ((f32x4*)ctab)[idx] = v;
}

// ---------------- gather-aggregate with fused BN(+relu) of source rows -------
// agg[n] = bn(hsrc[n]) + ctab[0] + sum_{edges} (bn(hsrc[src]) + ctab[feat])
// bn(x)[c] = relu?(x[c]*scale[c] + shift[c]);  ss = {scale[128], shift[128]}
__global__ __launch_bounds__(256) void gather_bn_kernel(
    const float* __restrict__ hsrc, float* __restrict__ agg,
    const int* __restrict__ rowstart, const int* __restrict__ rec,
    const float* __restrict__ ctab, const float* __restrict__ ss, int dorelu)
{
    int idx = blockIdx.x * 256 + threadIdx.x;   // NN*32
    int n = idx >> 5, q = idx & 31;
    f32x4 sc = ((const f32x4*)ss)[q];
    f32x4 sh = ((const f32x4*)(ss + 128))[q];
    int p0 = rowstart[n], p1 = rowstart[n + 1];
    f32x4 x = ((const f32x4*)(hsrc + n * DD))[q];
    f32x4 v = ((const f32x4*)ctab)[q];            // self_vec == ctab row 0
    #pragma unroll
    for (int j = 0; j < 4; ++j) {
        float t = x[j] * sc[j] + sh[j];
        if (dorelu && t < 0.f) t = 0.f;
        v[j] += t;
    }
    for (int p = p0; p < p1; ++p) {
        int r = rec[p];
        int s = r & 0x1FFFF;
        int f = ((unsigned)r) >> 17;
        f32x4 y = ((const f32x4*)(hsrc + s * DD))[q];
        f32x4 e = ((const f32x4*)(ctab + f * DD))[q];
        #pragma unroll
        for (int j = 0; j < 4; ++j) {
            float t = y[j] * sc[j] + sh[j];
            if (dorelu && t < 0.f) t = 0.f;
            v[j] += t + e[j];
        }
    }
    ((f32x4*)agg)[idx] = v;
}

// ---------------- fused MLP: hpre = relu(agg@W1+b1)@W2+b2, + column partials -
// 64 rows/block, hidden dim (256) processed in 4 chunks of 64.
// w1t fp16 [256][128] (=W1^T), w2t fp16 [128][256] (=W2^T).
__global__ __launch_bounds__(256) void mlp_kernel(
    const float* __restrict__ A, const _Float16* __restrict__ w1t,
    const _Float16* __restrict__ w2t,
    const float* __restrict__ b1, const float* __restrict__ b2,
    float* __restrict__ hpre, float* __restrict__ psum, float* __restrict__ psq,
    int M)
{
    __shared__ _Float16 w1c[64 * 136];   // chunk rows n1, k=0..127 (+8 pad)
    __shared__ _Float16 w2c[128 * 72];   // rows n2=0..127, k2 chunk (+8 pad)
    __shared__ _Float16 hid[64 * 72];    // wave-private hid tile (+8 pad)
    __shared__ float red[1024];          // cross-wave stat reduce
    int tid = threadIdx.x;
    int wave = tid >> 6, lane = tid & 63;
    int ln = lane & 15, quad = lane >> 4;
    int row0 = blockIdx.x * 64;
    int wrow0 = row0 + wave * 16;
    int m = wrow0 + ln;
    bool valid = m < M;

    // A-fragments: rows m, k = kb*32 + quad*8 + j  (fp32 -> fp16, in registers)
    f16x8 af[4];
    #pragma unroll
    for (int kb = 0; kb < 4; ++kb) {
        f16x8 a = {};
        if (valid) {
            const float* ap = A + m * 128 + kb * 32 + quad * 8;
            f32x4 a0 = *(const f32x4*)ap;
            f32x4 a1 = *(const f32x4*)(ap + 4);
            #pragma unroll
            for (int j = 0; j < 4; ++j) { a[j] = (_Float16)a0[j]; a[j + 4] = (_Float16)a1[j]; }
        }
        af[kb] = a;
    }

    f32x4 acc2[8] = {};
    for (int nc = 0; nc < 4; ++nc) {
        __syncthreads();                         // protect LDS re-stage
        for (int i = tid; i < 1024; i += 256) {  // w1c: 64 rows x 16 chunks
            int r = i >> 4, c = i & 15;
            *(f16x8*)(&w1c[r * 136 + c * 8]) =
                *(const f16x8*)(w1t + (nc * 64 + r) * 128 + c * 8);
        }
        for (int i = tid; i < 1024; i += 256) {  // w2c: 128 rows x 8 chunks
            int r = i >> 3, c = i & 7;
            *(f16x8*)(&w2c[r * 72 + c * 8]) =
                *(const f16x8*)(w2t + r * 256 + nc * 64 + c * 8);
        }
        __syncthreads();

        // GEMM1: hid_chunk[16x64 per wave] = A @ W1[:, chunk]
        f32x4 acc1[4] = {};
        #pragma unroll
        for (int kb = 0; kb < 4; ++kb) {
            #pragma unroll
            for (int nt = 0; nt < 4; ++nt) {
                f16x8 bf = *(const f16x8*)(&w1c[(nt * 16 + ln) * 136 + kb * 32 + quad * 8]);
                acc1[nt] = __builtin_amdgcn_mfma_f32_16x16x32_f16(af[kb], bf, acc1[nt], 0, 0, 0);
            }
        }
        // bias + relu -> wave-private LDS tile (C-layout -> A-layout transform)
        #pragma unroll
        for (int nt = 0; nt < 4; ++nt) {
            float bias = b1[nc * 64 + nt * 16 + ln];
            #pragma unroll
            for (int r = 0; r < 4; ++r) {
                float v = acc1[nt][r] + bias;
                v = v > 0.f ? v : 0.f;
                hid[(wave * 16 + quad * 4 + r) * 72 + nt * 16 + ln] = (_Float16)v;
            }
        }
        // GEMM2: acc2 += hid_chunk @ W2[chunk, :]
        #pragma unroll
        for (int kb2 = 0; kb2 < 2; ++kb2) {
            f16x8 a2 = *(const f16x8*)(&hid[(wave * 16 + ln) * 72 + kb2 * 32 + quad * 8]);
            #pragma unroll
            for (int nt2 = 0; nt2 < 8; ++nt2) {
                f16x8 bf = *(const f16x8*)(&w2c[(nt2 * 16 + ln) * 72 + kb2 * 32 + quad * 8]);
                acc2[nt2] = __builtin_amdgcn_mfma_f32_16x16x32_f16(a2, bf, acc2[nt2], 0, 0, 0);
            }
        }
    }

    // epilogue: bias, store hpre, per-block column partial sums (no atomics)
    #pragma unroll
    for (int nt2 = 0; nt2 < 8; ++nt2) {
        int n2 = nt2 * 16 + ln;
        float bias = b2[n2];
        float s = 0.f, q = 0.f;
        #pragma unroll
        for (int r = 0; r < 4; ++r) {
            int row = wrow0 + quad * 4 + r;
            if (row < M) {
                float v = acc2[nt2][r] + bias;
                hpre[row * 128 + n2] = v;
                s += v; q += v * v;
            }
        }
        s += __shfl_xor(s, 16, 64); s += __shfl_xor(s, 32, 64);
        q += __shfl_xor(q, 16, 64); q += __shfl_xor(q, 32, 64);
        if (quad == 0) {
            red[wave * 128 + n2] = s;
            red[512 + wave * 128 + n2] = q;
        }
    }
    __syncthreads();
    if (tid < 128) {
        float s = red[tid] + red[128 + tid] + red[256 + tid] + red[384 + tid];
        psum[blockIdx.x * 128 + tid] = s;
    } else {
        int c = tid - 128;
        float q = red[512 + c] + red[640 + c] + red[768 + c] + red[896 + c];
        psq[blockIdx.x * 128 + c] = q;
    }
}

// ---------------- fold partials -> scale/shift for BN ----------------
__global__ __launch_bounds__(256) void reduce_kernel(
    const float* __restrict__ psum, const float* __restrict__ psq,
    const float* __restrict__ gamma, const float* __restrict__ beta,
    float* __restrict__ ss, int nblk)
{
    int c = blockIdx.x;                  // 0..127
    int tid = threadIdx.x;
    float s = 0.f, q = 0.f;
    for (int b = tid; b < nblk; b += 256) {
        s += psum[b * 128 + c];
        q += psq[b * 128 + c];
    }
    #pragma unroll
    for (int off = 1; off < 64; off <<= 1) {
        s += __shfl_xor(s, off, 64);
        q += __shfl_xor(q, off, 64);
    }
    __shared__ float rs[4], rq[4];
    int wave = tid >> 6;
    if ((tid & 63) == 0) { rs[wave] = s; rq[wave] = q; }
    __syncthreads();
    if (tid == 0) {
        s = rs[0] + rs[1] + rs[2] + rs[3];
        q = rq[0] + rq[1] + rq[2] + rq[3];
        const float invN = 1.0f / NN;
        float mean = s * invN;
        float var = q * invN - mean * mean;
        float inv = rsqrtf(var + 1e-5f);
        float scale = gamma[c] * inv;
        ss[c] = scale;
        ss[128 + c] = beta[c] - mean * scale;
    }
}

// ---------------- final BN apply (no relu) -> d_out ----------------
__global__ __launch_bounds__(256) void final_bn_kernel(
    const float* __restrict__ hpre, float* __restrict__ out,
    const float* __restrict__ ss)
{
    int idx = blockIdx.x * 256 + threadIdx.x;   // NN*32
    int q = idx & 31;
    f32x4 x = ((const f32x4*)hpre)[idx];
    f32x4 sc = ((const f32x4*)ss)[q];
    f32x4 sh = ((const f32x4*)(ss + 128))[q];
    f32x4 y;
    #pragma unroll
    for (int j = 0; j < 4; ++j) y[j] = x[j] * sc[j] + sh[j];
    ((f32x4*)out)[idx] = y;
}

extern "C" void kernel_launch(void* const* d_in, const int* in_sizes, int n_in,
                              void* d_out, int out_size, void* d_ws, size_t ws_size,
                              hipStream_t stream)
{
    const int* an  = (const int*)d_in[0];
    const int* fc  = (const int*)d_in[1];
    const int* ct  = (const int*)d_in[2];
    const int* hy  = (const int*)d_in[3];
    const int* nh  = (const int*)d_in[4];
    const int* ar  = (const int*)d_in[5];
    const int* ei  = (const int*)d_in[6];
    const int* econ = (const int*)d_in[7];
    const int* earo = (const int*)d_in[8];
    const int* ebt  = (const int*)d_in[9];
    const int* ebd  = (const int*)d_in[10];
    const int* ebs  = (const int*)d_in[11];
    const float* ean = (const float*)d_in[12];
    const float* efc = (const float*)d_in[13];
    const float* ect = (const float*)d_in[14];
    const float* ehy = (const float*)d_in[15];
    const float* enh = (const float*)d_in[16];
    const float* ear = (const float*)d_in[17];
    const float* e_conj   = (const float*)d_in[18];
    const float* e_arom   = (const float*)d_in[19];
    const float* e_btype  = (const float*)d_in[20];
    const float* e_bdir   = (const float*)d_in[21];
    const float* e_bstereo= (const float*)d_in[22];
    const float* mlp_w1 = (const float*)d_in[23];
    const float* mlp_b1 = (const float*)d_in[24];
    const float* mlp_w2 = (const float*)d_in[25];
    const float* mlp_b2 = (const float*)d_in[26];
    const float* bn_gamma = (const float*)d_in[27];
    const float* bn_beta  = (const float*)d_in[28];

    // workspace carve (base 256B-aligned; segments keep 16B alignment)
    float*    h0   = (float*)d_ws;                      // N*128 f32 (seed)
    float*    agg  = h0 + NN * DD;                      // N*128 f32
    float*    hpre = agg + NN * DD;                     // N*128 f32
    _Float16* w1t  = (_Float16*)(hpre + NN * DD);       // 5*256*128 fp16
    _Float16* w2t  = w1t + LL * 256 * 128;              // 5*128*256 fp16
    float*    psum = (float*)(w2t + LL * 128 * 256);    // MBLK*128
    float*    psq  = psum + MBLK * 128;                 // MBLK*128
    float*    ss   = psq + MBLK * 128;                  // 256 (scale|shift)
    float*    idss = ss + 256;                          // 256 identity
    float*    ctab = idss + 256;                        // CTROWS*128 f32
    int* rowstart = (int*)(ctab + CTROWS * DD);         // NN+1
    int* cursor   = rowstart + NN + 8;                  // NN
    int* rec      = cursor + NN;                        // EE
    // total ~= 162 MB

    convw1_kernel<<<640, 256, 0, stream>>>(mlp_w1, w1t);
    convw2_kernel<<<640, 256, 0, stream>>>(mlp_w2, w2t);
    seed_kernel<<<12500, 256, 0, stream>>>(an, fc, ct, hy, nh, ar,
                                           ean, efc, ect, ehy, enh, ear, h0);
    idss_kernel<<<1, 256, 0, stream>>>(idss);

    // CSR build (re-run every call: ws is re-poisoned)
    hipMemsetAsync(cursor, 0, NN * sizeof(int), stream);
    count_kernel<<<2344, 256, 0, stream>>>(ei, cursor);
    scan_kernel<<<1, 1024, 0, stream>>>(cursor, rowstart);
    fill_kernel<<<2344, 256, 0, stream>>>(ei, cursor, rec,
                                          econ, earo, ebt, ebd, ebs);

    for (int l = 0; l < LL; ++l) {
        ctab_kernel<<<644, 256, 0, stream>>>(
            e_conj + l * 3 * DD, e_arom + l * 3 * DD, e_btype + l * 23 * DD,
            e_bdir + l * 8 * DD, e_bstereo + l * 7 * DD, ctab);
        // layer 0 reads raw seed h (identity transform, no relu);
        // layers 1+ read prev hpre with fused BN+relu
        gather_bn_kernel<<<12500, 256, 0, stream>>>(
            (l == 0) ? h0 : hpre, agg, rowstart, rec, ctab,
            (l == 0) ? idss : ss, (l == 0) ? 0 : 1);
        mlp_kernel<<<MBLK, 256, 0, stream>>>(
            agg, w1t + l * 32768, w2t + l * 32768,
            mlp_b1 + l * 256, mlp_b2 + l * 128,
            hpre, psum, psq, NN);
        reduce_kernel<<<128, 256, 0, stream>>>(
            psum, psq, bn_gamma + l * 128, bn_beta + l * 128, ss, MBLK);
    }
    final_bn_kernel<<<12500, 256, 0, stream>>>(hpre, (float*)d_out, ss);
}

// Round 4
// 738.774 us; speedup vs baseline: 9.4652x; 1.4881x over previous
//
#include <hip/hip_runtime.h>

#define NN 100000
#define EE 600000
#define DD 128
#define LL 5
#define CTROWS 5152   // 2*2*23*8*7 combined edge-feature rows
#define MBLK 1563     // ceil(NN/64)
#define SBLK 98       // scan blocks: 98*1024 >= NN

typedef float f32x4 __attribute__((ext_vector_type(4)));
typedef _Float16 f16x8 __attribute__((ext_vector_type(8)));

// ---------------- seed: h = sum of 6 atom-feature embeddings (fp16 out) ------
__global__ __launch_bounds__(256) void seed_kernel(
    const int* __restrict__ an, const int* __restrict__ fc,
    const int* __restrict__ ct, const int* __restrict__ hy,
    const int* __restrict__ nh, const int* __restrict__ ar,
    const float* __restrict__ ean, const float* __restrict__ efc,
    const float* __restrict__ ect, const float* __restrict__ ehy,
    const float* __restrict__ enh, const float* __restrict__ ear,
    _Float16* __restrict__ h)
{
    int idx = blockIdx.x * 256 + threadIdx.x;   // NN*16 exactly
    int n = idx >> 4, q = idx & 15;
    f32x4 a0 = ((const f32x4*)(ean + an[n] * DD))[2 * q];
    f32x4 a1 = ((const f32x4*)(ean + an[n] * DD))[2 * q + 1];
    a0 += ((const f32x4*)(efc + fc[n] * DD))[2 * q];
    a1 += ((const f32x4*)(efc + fc[n] * DD))[2 * q + 1];
    a0 += ((const f32x4*)(ect + ct[n] * DD))[2 * q];
    a1 += ((const f32x4*)(ect + ct[n] * DD))[2 * q + 1];
    a0 += ((const f32x4*)(ehy + hy[n] * DD))[2 * q];
    a1 += ((const f32x4*)(ehy + hy[n] * DD))[2 * q + 1];
    a0 += ((const f32x4*)(enh + nh[n] * DD))[2 * q];
    a1 += ((const f32x4*)(enh + nh[n] * DD))[2 * q + 1];
    a0 += ((const f32x4*)(ear + ar[n] * DD))[2 * q];
    a1 += ((const f32x4*)(ear + ar[n] * DD))[2 * q + 1];
    f16x8 o;
    #pragma unroll
    for (int j = 0; j < 4; ++j) { o[j] = (_Float16)a0[j]; o[j + 4] = (_Float16)a1[j]; }
    ((f16x8*)h)[idx] = o;
}

// ---------------- weight convert+transpose to fp16 [n][k] ----------------
__global__ __launch_bounds__(256) void convw1_kernel(const float* __restrict__ w1,
                                                     _Float16* __restrict__ w1t)
{
    int idx = blockIdx.x * 256 + threadIdx.x;   // 5*256*128
    int l = idx >> 15, rem = idx & 32767;
    int n = rem >> 7, k = rem & 127;
    w1t[idx] = (_Float16)w1[l * 32768 + k * 256 + n];
}
__global__ __launch_bounds__(256) void convw2_kernel(const float* __restrict__ w2,
                                                     _Float16* __restrict__ w2t)
{
    int idx = blockIdx.x * 256 + threadIdx.x;   // 5*128*256
    int l = idx >> 15, rem = idx & 32767;
    int n = rem >> 8, k = rem & 255;
    w2t[idx] = (_Float16)w2[l * 32768 + k * 128 + n];
}

// ---------------- identity scale/shift for layer-0 gather ----------------
__global__ void idss_kernel(float* __restrict__ idss)
{
    int t = threadIdx.x;
    idss[t] = (t < 128) ? 1.0f : 0.0f;
}

// ---------------- CSR build: count, 3-phase scan, fill ----------------
__global__ __launch_bounds__(256) void count_kernel(const int* __restrict__ ei,
                                                    int* __restrict__ cursor)
{
    int e = blockIdx.x * 256 + threadIdx.x;
    if (e < EE) atomicAdd(&cursor[ei[EE + e]], 1);
}

// phase A: per-block (1024-elem chunk) totals
__global__ __launch_bounds__(1024) void btot_kernel(const int* __restrict__ cursor,
                                                    int* __restrict__ btot)
{
    __shared__ int wsum[16];
    int tid = threadIdx.x;
    int i = blockIdx.x * 1024 + tid;
    int x = (i < NN) ? cursor[i] : 0;
    #pragma unroll
    for (int off = 1; off < 64; off <<= 1) x += __shfl_xor(x, off, 64);
    if ((tid & 63) == 0) wsum[tid >> 6] = x;
    __syncthreads();
    if (tid == 0) {
        int s = 0;
        #pragma unroll
        for (int w = 0; w < 16; ++w) s += wsum[w];
        btot[blockIdx.x] = s;
    }
}

// phase B: scan SBLK block totals (1 small block, 2 waves)
__global__ __launch_bounds__(128) void bscan_kernel(const int* __restrict__ btot,
                                                    int* __restrict__ boff,
                                                    int* __restrict__ rowstart)
{
    __shared__ int w0;
    int t = threadIdx.x;
    int lane = t & 63, wv = t >> 6;
    int x = (t < SBLK) ? btot[t] : 0;
    int incl = x;
    #pragma unroll
    for (int off = 1; off < 64; off <<= 1) {
        int u = __shfl_up(incl, off, 64);
        if (lane >= off) incl += u;
    }
    if (wv == 0 && lane == 63) w0 = incl;
    __syncthreads();
    if (wv == 1) incl += w0;
    if (t < SBLK) boff[t] = incl - x;
    if (t == 127) rowstart[NN] = incl;   // grand total
}

// phase C: block-local scan + block offset -> rowstart & cursor
__global__ __launch_bounds__(1024) void apply_kernel(const int* __restrict__ cursorin,
                                                     const int* __restrict__ boff,
                                                     int* __restrict__ rowstart,
                                                     int* __restrict__ cursor)
{
    __shared__ int wsum[16];
    int tid = threadIdx.x;
    int lane = tid & 63, wv = tid >> 6;
    int i = blockIdx.x * 1024 + tid;
    int x = (i < NN) ? cursorin[i] : 0;
    int incl = x;
    #pragma unroll
    for (int off = 1; off < 64; off <<= 1) {
        int u = __shfl_up(incl, off, 64);
        if (lane >= off) incl += u;
    }
    if (lane == 63) wsum[wv] = incl;
    __syncthreads();
    int pre = 0;
    #pragma unroll
    for (int w = 0; w < 16; ++w) pre += (w < wv) ? wsum[w] : 0;
    int excl = boff[blockIdx.x] + pre + incl - x;
    if (i < NN) { rowstart[i] = excl; cursor[i] = excl; }
}

__global__ __launch_bounds__(256) void fill_kernel(
    const int* __restrict__ ei, int* __restrict__ cursor, int* __restrict__ rec,
    const int* __restrict__ f0, const int* __restrict__ f1,
    const int* __restrict__ f2, const int* __restrict__ f3,
    const int* __restrict__ f4)
{
    int e = blockIdx.x * 256 + threadIdx.x;
    if (e >= EE) return;
    int dst = ei[EE + e];
    int p = atomicAdd(&cursor[dst], 1);
    int f = f0[e] + 2 * (f1[e] + 2 * (f2[e] + 23 * (f3[e] + 8 * f4[e])));
    rec[p] = ei[e] | (f << 17);
}

// ---------------- combined edge-embedding table (fp16 out) ----------------
__global__ __launch_bounds__(256) void ctab_kernel(
    const float* __restrict__ ec, const float* __restrict__ ea,
    const float* __restrict__ eb, const float* __restrict__ ed,
    const float* __restrict__ es, _Float16* __restrict__ ctab)
{
    int idx = blockIdx.x * 256 + threadIdx.x;   // CTROWS*16 exactly
    int row = idx >> 4, q = idx & 15;
    int conj = row & 1, arom = (row >> 1) & 1;
    int r2 = row >> 2;
    int bt = r2 % 23, r3 = r2 / 23;
    int bd = r3 & 7, bs = r3 >> 3;
    f32x4 a0 = ((const f32x4*)(ec + conj * DD))[2 * q]
             + ((const f32x4*)(ea + arom * DD))[2 * q]
             + ((const f32x4*)(eb + bt * DD))[2 * q]
             + ((const f32x4*)(ed + bd * DD))[2 * q]
             + ((const f32x4*)(es + bs * DD))[2 * q];
    f32x4 a1 = ((const f32x4*)(ec + conj * DD))[2 * q + 1]
             + ((const f32x4*)(ea + arom * DD))[2 * q + 1]
             + ((const f32x4*)(eb + bt * DD))[2 * q + 1]
             + ((const f32x4*)(ed + bd * DD))[2 * q + 1]
             + ((const f32x4*)(es + bs * DD))[2 * q + 1];
    f16x8 o;
    #pragma unroll
    for (int j = 0; j < 4; ++j) { o[j] = (_Float16)a0[j]; o[j + 4] = (_Float16)a1[j]; }
    ((f16x8*)ctab)[idx] = o;
}

// ---------------- gather-aggregate with fused BN(+relu), fp16 in/out ---------
// agg[n] = bn(hsrc[n]) + ctab[0] + sum_{edges}(bn(hsrc[src]) + ctab[feat])
__global__ __launch_bounds__(256) void gather_bn_kernel(
    const _Float16* __restrict__ hsrc, _Float16* __restrict__ agg,
    const int* __restrict__ rowstart, const int* __restrict__ rec,
    const _Float16* __restrict__ ctab, const float* __restrict__ ss, int dorelu)
{
    int idx = blockIdx.x * 256 + threadIdx.x;   // NN*16
    int n = idx >> 4, q = idx & 15;
    f32x4 sc0 = ((const f32x4*)ss)[2 * q],        sc1 = ((const f32x4*)ss)[2 * q + 1];
    f32x4 sh0 = ((const f32x4*)(ss + 128))[2 * q], sh1 = ((const f32x4*)(ss + 128))[2 * q + 1];
    int p0 = rowstart[n], p1 = rowstart[n + 1];
    f16x8 x = ((const f16x8*)hsrc)[idx];
    f16x8 c0 = ((const f16x8*)ctab)[q];           // self_vec == ctab row 0
    float v[8];
    #pragma unroll
    for (int j = 0; j < 8; ++j) {
        float sc = (j < 4) ? sc0[j] : sc1[j - 4];
        float sh = (j < 4) ? sh0[j] : sh1[j - 4];
        float t = (float)x[j] * sc + sh;
        if (dorelu && t < 0.f) t = 0.f;
        v[j] = t + (float)c0[j];
    }
    for (int p = p0; p < p1; ++p) {
        int r = rec[p];
        int s = r & 0x1FFFF;
        int f = ((unsigned)r) >> 17;
        f16x8 y = *(const f16x8*)(hsrc + s * DD + q * 8);
        f16x8 e = *(const f16x8*)(ctab + f * DD + q * 8);
        #pragma unroll
        for (int j = 0; j < 8; ++j) {
            float sc = (j < 4) ? sc0[j] : sc1[j - 4];
            float sh = (j < 4) ? sh0[j] : sh1[j - 4];
            float t = (float)y[j] * sc + sh;
            if (dorelu && t < 0.f) t = 0.f;
            v[j] += t + (float)e[j];
        }
    }
    f16x8 o;
    #pragma unroll
    for (int j = 0; j < 8; ++j) o[j] = (_Float16)v[j];
    ((f16x8*)agg)[idx] = o;
}

// ---------------- fused MLP: hpre = relu(agg@W1+b1)@W2+b2 + column partials --
// A fp16 [M][128]; w1t fp16 [256][128] (=W1^T); w2t fp16 [128][256] (=W2^T).
__global__ __launch_bounds__(256) void mlp_kernel(
    const _Float16* __restrict__ A, const _Float16* __restrict__ w1t,
    const _Float16* __restrict__ w2t,
    const float* __restrict__ b1, const float* __restrict__ b2,
    _Float16* __restrict__ hpre, float* __restrict__ psum, float* __restrict__ psq,
    int M)
{
    __shared__ _Float16 w1c[64 * 136];   // chunk rows n1, k=0..127 (+8 pad)
    __shared__ _Float16 w2c[128 * 72];   // rows n2=0..127, k2 chunk (+8 pad)
    __shared__ _Float16 hid[64 * 72];    // wave-private hid tile (+8 pad)
    __shared__ float red[1024];          // cross-wave stat reduce
    int tid = threadIdx.x;
    int wave = tid >> 6, lane = tid & 63;
    int ln = lane & 15, quad = lane >> 4;
    int wrow0 = blockIdx.x * 64 + wave * 16;
    int m = wrow0 + ln;
    bool valid = m < M;

    f16x8 af[4];
    #pragma unroll
    for (int kb = 0; kb < 4; ++kb) {
        f16x8 a = {};
        if (valid) a = *(const f16x8*)(A + m * 128 + kb * 32 + quad * 8);
        af[kb] = a;
    }

    f32x4 acc2[8] = {};
    for (int nc = 0; nc < 4; ++nc) {
        __syncthreads();
        for (int i = tid; i < 1024; i += 256) {  // w1c: 64 rows x 16 chunks
            int r = i >> 4, c = i & 15;
            *(f16x8*)(&w1c[r * 136 + c * 8]) =
                *(const f16x8*)(w1t + (nc * 64 + r) * 128 + c * 8);
        }
        for (int i = tid; i < 1024; i += 256) {  // w2c: 128 rows x 8 chunks
            int r = i >> 3, c = i & 7;
            *(f16x8*)(&w2c[r * 72 + c * 8]) =
                *(const f16x8*)(w2t + r * 256 + nc * 64 + c * 8);
        }
        __syncthreads();

        f32x4 acc1[4] = {};
        #pragma unroll
        for (int kb = 0; kb < 4; ++kb) {
            #pragma unroll
            for (int nt = 0; nt < 4; ++nt) {
                f16x8 bf = *(const f16x8*)(&w1c[(nt * 16 + ln) * 136 + kb * 32 + quad * 8]);
                acc1[nt] = __builtin_amdgcn_mfma_f32_16x16x32_f16(af[kb], bf, acc1[nt], 0, 0, 0);
            }
        }
        #pragma unroll
        for (int nt = 0; nt < 4; ++nt) {
            float bias = b1[nc * 64 + nt * 16 + ln];
            #pragma unroll
            for (int r = 0; r < 4; ++r) {
                float v = acc1[nt][r] + bias;
                v = v > 0.f ? v : 0.f;
                hid[(wave * 16 + quad * 4 + r) * 72 + nt * 16 + ln] = (_Float16)v;
            }
        }
        #pragma unroll
        for (int kb2 = 0; kb2 < 2; ++kb2) {
            f16x8 a2 = *(const f16x8*)(&hid[(wave * 16 + ln) * 72 + kb2 * 32 + quad * 8]);
            #pragma unroll
            for (int nt2 = 0; nt2 < 8; ++nt2) {
                f16x8 bf = *(const f16x8*)(&w2c[(nt2 * 16 + ln) * 72 + kb2 * 32 + quad * 8]);
                acc2[nt2] = __builtin_amdgcn_mfma_f32_16x16x32_f16(a2, bf, acc2[nt2], 0, 0, 0);
            }
        }
    }

    #pragma unroll
    for (int nt2 = 0; nt2 < 8; ++nt2) {
        int n2 = nt2 * 16 + ln;
        float bias = b2[n2];
        float s = 0.f, q = 0.f;
        #pragma unroll
        for (int r = 0; r < 4; ++r) {
            int row = wrow0 + quad * 4 + r;
            if (row < M) {
                float v = acc2[nt2][r] + bias;
                hpre[row * 128 + n2] = (_Float16)v;
                s += v; q += v * v;
            }
        }
        s += __shfl_xor(s, 16, 64); s += __shfl_xor(s, 32, 64);
        q += __shfl_xor(q, 16, 64); q += __shfl_xor(q, 32, 64);
        if (quad == 0) {
            red[wave * 128 + n2] = s;
            red[512 + wave * 128 + n2] = q;
        }
    }
    __syncthreads();
    if (tid < 128) {
        float s = red[tid] + red[128 + tid] + red[256 + tid] + red[384 + tid];
        psum[blockIdx.x * 128 + tid] = s;
    } else {
        int c = tid - 128;
        float q = red[512 + c] + red[640 + c] + red[768 + c] + red[896 + c];
        psq[blockIdx.x * 128 + c] = q;
    }
}

// ---------------- fold partials -> scale/shift for BN ----------------
__global__ __launch_bounds__(256) void reduce_kernel(
    const float* __restrict__ psum, const float* __restrict__ psq,
    const float* __restrict__ gamma, const float* __restrict__ beta,
    float* __restrict__ ss, int nblk)
{
    int c = blockIdx.x;                  // 0..127
    int tid = threadIdx.x;
    float s = 0.f, q = 0.f;
    for (int b = tid; b < nblk; b += 256) {
        s += psum[b * 128 + c];
        q += psq[b * 128 + c];
    }
    #pragma unroll
    for (int off = 1; off < 64; off <<= 1) {
        s += __shfl_xor(s, off, 64);
        q += __shfl_xor(q, off, 64);
    }
    __shared__ float rs[4], rq[4];
    int wave = tid >> 6;
    if ((tid & 63) == 0) { rs[wave] = s; rq[wave] = q; }
    __syncthreads();
    if (tid == 0) {
        s = rs[0] + rs[1] + rs[2] + rs[3];
        q = rq[0] + rq[1] + rq[2] + rq[3];
        const float invN = 1.0f / NN;
        float mean = s * invN;
        float var = q * invN - mean * mean;
        float inv = rsqrtf(var + 1e-5f);
        float scale = gamma[c] * inv;
        ss[c] = scale;
        ss[128 + c] = beta[c] - mean * scale;
    }
}

// ---------------- final BN apply (no relu) -> fp32 d_out ----------------
__global__ __launch_bounds__(256) void final_bn_kernel(
    const _Float16* __restrict__ hpre, float* __restrict__ out,
    const float* __restrict__ ss)
{
    int idx = blockIdx.x * 256 + threadIdx.x;   // NN*16
    int q = idx & 15;
    f16x8 x = ((const f16x8*)hpre)[idx];
    f32x4 sc0 = ((const f32x4*)ss)[2 * q],        sc1 = ((const f32x4*)ss)[2 * q + 1];
    f32x4 sh0 = ((const f32x4*)(ss + 128))[2 * q], sh1 = ((const f32x4*)(ss + 128))[2 * q + 1];
    f32x4 y0, y1;
    #pragma unroll
    for (int j = 0; j < 4; ++j) {
        y0[j] = (float)x[j] * sc0[j] + sh0[j];
        y1[j] = (float)x[j + 4] * sc1[j] + sh1[j];
    }
    ((f32x4*)out)[2 * idx] = y0;
    ((f32x4*)out)[2 * idx + 1] = y1;
}

extern "C" void kernel_launch(void* const* d_in, const int* in_sizes, int n_in,
                              void* d_out, int out_size, void* d_ws, size_t ws_size,
                              hipStream_t stream)
{
    const int* an  = (const int*)d_in[0];
    const int* fc  = (const int*)d_in[1];
    const int* ct  = (const int*)d_in[2];
    const int* hy  = (const int*)d_in[3];
    const int* nh  = (const int*)d_in[4];
    const int* ar  = (const int*)d_in[5];
    const int* ei  = (const int*)d_in[6];
    const int* econ = (const int*)d_in[7];
    const int* earo = (const int*)d_in[8];
    const int* ebt  = (const int*)d_in[9];
    const int* ebd  = (const int*)d_in[10];
    const int* ebs  = (const int*)d_in[11];
    const float* ean = (const float*)d_in[12];
    const float* efc = (const float*)d_in[13];
    const float* ect = (const float*)d_in[14];
    const float* ehy = (const float*)d_in[15];
    const float* enh = (const float*)d_in[16];
    const float* ear = (const float*)d_in[17];
    const float* e_conj   = (const float*)d_in[18];
    const float* e_arom   = (const float*)d_in[19];
    const float* e_btype  = (const float*)d_in[20];
    const float* e_bdir   = (const float*)d_in[21];
    const float* e_bstereo= (const float*)d_in[22];
    const float* mlp_w1 = (const float*)d_in[23];
    const float* mlp_b1 = (const float*)d_in[24];
    const float* mlp_w2 = (const float*)d_in[25];
    const float* mlp_b2 = (const float*)d_in[26];
    const float* bn_gamma = (const float*)d_in[27];
    const float* bn_beta  = (const float*)d_in[28];

    // workspace carve (base 256B-aligned; all segments stay 16B-aligned)
    _Float16* h0   = (_Float16*)d_ws;                   // N*128 fp16
    _Float16* agg  = h0 + (size_t)NN * DD;              // N*128 fp16
    _Float16* hpre = agg + (size_t)NN * DD;             // N*128 fp16
    _Float16* w1t  = hpre + (size_t)NN * DD;            // 5*256*128 fp16
    _Float16* w2t  = w1t + LL * 256 * 128;              // 5*128*256 fp16
    _Float16* ctab = w2t + LL * 128 * 256;              // CTROWS*128 fp16
    float*    psum = (float*)(ctab + CTROWS * DD);      // MBLK*128
    float*    psq  = psum + MBLK * 128;                 // MBLK*128
    float*    ss   = psq + MBLK * 128;                  // 256 (scale|shift)
    float*    idss = ss + 256;                          // 256 identity
    int* rowstart = (int*)(idss + 256);                 // NN+1
    int* cursor   = rowstart + NN + 8;                  // NN
    int* rec      = cursor + NN;                        // EE
    int* btot     = rec + EE;                           // SBLK
    int* boff     = btot + SBLK + 8;                    // SBLK
    // total ~= 86 MB

    convw1_kernel<<<640, 256, 0, stream>>>(mlp_w1, w1t);
    convw2_kernel<<<640, 256, 0, stream>>>(mlp_w2, w2t);
    seed_kernel<<<6250, 256, 0, stream>>>(an, fc, ct, hy, nh, ar,
                                          ean, efc, ect, ehy, enh, ear, h0);
    idss_kernel<<<1, 256, 0, stream>>>(idss);

    // CSR build (re-run every call: ws is re-poisoned)
    hipMemsetAsync(cursor, 0, NN * sizeof(int), stream);
    count_kernel<<<2344, 256, 0, stream>>>(ei, cursor);
    btot_kernel<<<SBLK, 1024, 0, stream>>>(cursor, btot);
    bscan_kernel<<<1, 128, 0, stream>>>(btot, boff, rowstart);
    apply_kernel<<<SBLK, 1024, 0, stream>>>(cursor, boff, rowstart, cursor);
    fill_kernel<<<2344, 256, 0, stream>>>(ei, cursor, rec,
                                          econ, earo, ebt, ebd, ebs);

    for (int l = 0; l < LL; ++l) {
        ctab_kernel<<<322, 256, 0, stream>>>(
            e_conj + l * 3 * DD, e_arom + l * 3 * DD, e_btype + l * 23 * DD,
            e_bdir + l * 8 * DD, e_bstereo + l * 7 * DD, ctab);
        gather_bn_kernel<<<6250, 256, 0, stream>>>(
            (l == 0) ? h0 : hpre, agg, rowstart, rec, ctab,
            (l == 0) ? idss : ss, (l == 0) ? 0 : 1);
        mlp_kernel<<<MBLK, 256, 0, stream>>>(
            agg, w1t + l * 32768, w2t + l * 32768,
            mlp_b1 + l * 256, mlp_b2 + l * 128,
            hpre, psum, psq, NN);
        reduce_kernel<<<128, 256, 0, stream>>>(
            psum, psq, bn_gamma + l * 128, bn_beta + l * 128, ss, MBLK);
    }
    final_bn_kernel<<<6250, 256, 0, stream>>>(hpre, (float*)d_out, ss);
}